// Round 10
// baseline (32.078 us; speedup 1.0000x reference)
//
#include <hip/hip_runtime.h>

#define PS    25
#define PADW  12
#define EPSV  (1.0f/255.0f)
#define WW    512
#define HH    512
#define NB    16

#define TW    64                 // output tile width
#define TH    32                 // output tile height
#define IWn   (TW + 2*PADW)      // 88 halo cols
#define IHn   (TH + 2*PADW)      // 56 halo rows
#define IWS   88                 // LDS stride (mult of 4 -> b128-aligned)
#define NPX   (IWn * IHn)        // 4928 halo pixels (scalar path)
#define NPX4  (IHn * (IWn/4))    // 1232 float4 groups (fast path)
#define NCG   (IWn/4)            // 22 column groups
#define NT2   (2 * NCG)          // 44 stage-2 tasks

#define INV625 (1.0f/625.0f)

__device__ __forceinline__ int reflectI(int i, int n) {
    if (i < 0)  i = -i;
    if (i >= n) i = 2 * n - 2 - i;
    return i;
}

__device__ __forceinline__ float fastrcp(float x) {
    float y;
    asm("v_rcp_f32 %0, %1" : "=v"(y) : "v"(x));
    return y;
}

__global__ __launch_bounds__(512, 8)
void fused_tile(const float* __restrict__ img, float* __restrict__ out)
{
    const int t  = threadIdx.x;
    const int x0 = blockIdx.x * TW;
    const int y0 = blockIdx.y * TH;
    const int b  = blockIdx.z;

    // rows 0..31 get overwritten by vertical 25-tap sums in stage 2 (in-place)
    __shared__ float smM[IHn][IWS];   // channel-mean            (56x88)
    __shared__ float smS[IHn][IWS];   // channel-mean of squares (56x88)

    const size_t plane = (size_t)WW * HH;
    const float* pR = img + (size_t)b * 3 * plane;
    const float* pG = pR + plane;
    const float* pB = pR + 2 * plane;

    const bool interior = (x0 >= PADW) && (x0 + TW + PADW <= WW) &&
                          (y0 >= PADW) && (y0 + TH + PADW <= HH);

    // ---- stage 1: load halo, compute m,s into LDS ----
    if (interior) {
        const size_t base = (size_t)(y0 - PADW) * WW + (x0 - PADW);
        for (int i = t; i < NPX4; i += 512) {
            int iy = i / NCG;              // 0..55
            int ix = (i - iy * NCG) * 4;   // 0,4,...,84
            size_t off = base + (size_t)(iy << 9) + ix;
            float4 ra = *(const float4*)(pR + off);
            float4 ga = *(const float4*)(pG + off);
            float4 ba = *(const float4*)(pB + off);
            float r[4]  = {ra.x, ra.y, ra.z, ra.w};
            float g[4]  = {ga.x, ga.y, ga.z, ga.w};
            float bl[4] = {ba.x, ba.y, ba.z, ba.w};
            float m[4], s[4];
#pragma unroll
            for (int j = 0; j < 4; ++j) {
                m[j] = (r[j] + g[j] + bl[j]) * (1.0f/3.0f);
                s[j] = fmaf(r[j], r[j], fmaf(g[j], g[j], bl[j]*bl[j])) * (1.0f/3.0f);
            }
            *(float4*)&smM[iy][ix] = make_float4(m[0], m[1], m[2], m[3]);
            *(float4*)&smS[iy][ix] = make_float4(s[0], s[1], s[2], s[3]);
        }
    } else {
        for (int i = t; i < NPX; i += 512) {
            int iy = i / IWn;
            int ix = i - iy * IWn;
            int gy = reflectI(y0 - PADW + iy, HH);
            int gx = reflectI(x0 - PADW + ix, WW);
            size_t idx = (size_t)gy * WW + gx;
            float r  = pR[idx];
            float g  = pG[idx];
            float bl = pB[idx];
            smM[iy][ix] = (r + g + bl) * (1.0f/3.0f);
            smS[iy][ix] = fmaf(r, r, fmaf(g, g, bl*bl)) * (1.0f/3.0f);
        }
    }
    __syncthreads();

    // ---- stage 2: vertical 25-tap float4 in-place forward scan (44 tasks) ----
    if (t < NT2) {
        int rem = t;
        float (*buf)[IWS] = smM;
        if (rem >= NCG) { buf = smS; rem -= NCG; }
        const int xb = rem * 4;

        float4 old = *(const float4*)&buf[0][xb];   // original row 0
        float4 run = old;
#pragma unroll
        for (int k = 1; k < PS; ++k) {
            float4 v = *(const float4*)&buf[k][xb];
            run.x += v.x; run.y += v.y; run.z += v.z; run.w += v.w;
        }
        *(float4*)&buf[0][xb] = run;
#pragma unroll
        for (int y = 1; y < TH; ++y) {
            float4 cur = *(const float4*)&buf[y][xb];        // original value
            float4 nw  = *(const float4*)&buf[y + PS - 1][xb];
            run.x += nw.x - old.x; run.y += nw.y - old.y;
            run.z += nw.z - old.z; run.w += nw.w - old.w;
            *(float4*)&buf[y][xb] = run;                     // forward-safe
            old = cur;
        }
    }
    __syncthreads();

    // ---- stage 3: horizontal 25-tap + sat + final (512 tasks exactly) ----
    const int r  = t >> 4;          // 0..31 output row
    const int c4 = (t & 15) * 4;    // 0..60 output col group

    // issue sat global loads FIRST so their latency hides under the LDS reads
    const size_t ro = (size_t)(y0 + r) * WW + x0 + c4;
    const float4 ra = *(const float4*)(pR + ro);
    const float4 ga = *(const float4*)(pG + ro);
    const float4 ba = *(const float4*)(pB + ro);

    float wm[28], ws[28];
#pragma unroll
    for (int i = 0; i < 7; ++i) {
        float4 a = *(const float4*)&smM[r][c4 + 4*i];
        float4 c = *(const float4*)&smS[r][c4 + 4*i];
        wm[4*i]=a.x; wm[4*i+1]=a.y; wm[4*i+2]=a.z; wm[4*i+3]=a.w;
        ws[4*i]=c.x; ws[4*i+1]=c.y; ws[4*i+2]=c.z; ws[4*i+3]=c.w;
    }
    float hm = 0.f, hs = 0.f;
#pragma unroll
    for (int i = 0; i < PS; ++i) { hm += wm[i]; hs += ws[i]; }

    float rr[4] = {ra.x, ra.y, ra.z, ra.w};
    float gg[4] = {ga.x, ga.y, ga.z, ga.w};
    float bb[4] = {ba.x, ba.y, ba.z, ba.w};

    float sc[4];
#pragma unroll
    for (int j = 0; j < 4; ++j) {
        if (j > 0) {
            hm += wm[PS - 1 + j] - wm[j - 1];
            hs += ws[PS - 1 + j] - ws[j - 1];
        }
        float mx = fmaxf(rr[j], fmaxf(gg[j], bb[j]));
        float mn = fminf(rr[j], fminf(gg[j], bb[j]));
        float sat = (mx - mn + EPSV) * fastrcp(mx + EPSV);

        float mean     = hm * INV625;
        float msq      = hs * INV625;
        float contrast = fmaf(-mean, mean, msq);
        float expo     = fabsf(mean - 0.5f) + EPSV;
        sc[j] = sat * contrast * fastrcp(expo);
    }
    float* orow = out + ((size_t)b * HH + (y0 + r)) * WW + x0 + c4;
    *(float4*)orow = make_float4(sc[0], sc[1], sc[2], sc[3]);
}

extern "C" void kernel_launch(void* const* d_in, const int* in_sizes, int n_in,
                              void* d_out, int out_size, void* d_ws, size_t ws_size,
                              hipStream_t stream)
{
    const float* img = (const float*)d_in[0];
    float* out = (float*)d_out;

    dim3 grid(WW / TW, HH / TH, NB);   // 8 x 16 x 16 = 2048 blocks
    fused_tile<<<grid, 512, 0, stream>>>(img, out);
}

// Round 11
// 30.705 us; speedup vs baseline: 1.0447x; 1.0447x over previous
//
#include <hip/hip_runtime.h>

#define PS    25
#define PADW  12
#define EPSV  (1.0f/255.0f)
#define WW    512
#define HH    512
#define NB    16

#define TW    64                 // output tile width
#define TH    32                 // output tile height
#define IWn   (TW + 2*PADW)      // 88 halo cols
#define IHn   (TH + 2*PADW)      // 56 halo rows
#define IWS   88                 // LDS stride (mult of 4 -> b128-aligned)
#define NPX   (IWn * IHn)        // 4928 halo pixels (scalar path)
#define NPX4  (IHn * (IWn/4))    // 1232 float4 groups (fast path)
#define NCG   (IWn/4)            // 22 column groups
#define NT2   (4 * IWn)          // 352 stage-2 tasks: {m,s} x {seg0,seg1} x 88 cols

#define INV625 (1.0f/625.0f)

__device__ __forceinline__ int reflectI(int i, int n) {
    if (i < 0)  i = -i;
    if (i >= n) i = 2 * n - 2 - i;
    return i;
}

__device__ __forceinline__ float fastrcp(float x) {
    float y;
    asm("v_rcp_f32 %0, %1" : "=v"(y) : "v"(x));
    return y;
}

__global__ __launch_bounds__(512, 8)
void fused_tile(const float* __restrict__ img, float* __restrict__ out)
{
    const int t  = threadIdx.x;
    const int x0 = blockIdx.x * TW;
    const int y0 = blockIdx.y * TH;
    const int b  = blockIdx.z;

    // stage 2 overwrites rows 0..15 (seg0, in place) and rows 40..55 (seg1's
    // vertical sums, parked in the dead tail halo) -- hazard-free forward scans.
    __shared__ float smM[IHn][IWS];   // channel-mean            (56x88)
    __shared__ float smS[IHn][IWS];   // channel-mean of squares (56x88)

    const size_t plane = (size_t)WW * HH;
    const float* pR = img + (size_t)b * 3 * plane;
    const float* pG = pR + plane;
    const float* pB = pR + 2 * plane;

    const bool interior = (x0 >= PADW) && (x0 + TW + PADW <= WW) &&
                          (y0 >= PADW) && (y0 + TH + PADW <= HH);

    // ---- stage 1: load halo, compute m,s into LDS ----
    if (interior) {
        const size_t base = (size_t)(y0 - PADW) * WW + (x0 - PADW);
        for (int i = t; i < NPX4; i += 512) {
            int iy = i / NCG;              // 0..55
            int ix = (i - iy * NCG) * 4;   // 0,4,...,84
            size_t off = base + (size_t)(iy << 9) + ix;
            float4 ra = *(const float4*)(pR + off);
            float4 ga = *(const float4*)(pG + off);
            float4 ba = *(const float4*)(pB + off);
            float r[4]  = {ra.x, ra.y, ra.z, ra.w};
            float g[4]  = {ga.x, ga.y, ga.z, ga.w};
            float bl[4] = {ba.x, ba.y, ba.z, ba.w};
            float m[4], s[4];
#pragma unroll
            for (int j = 0; j < 4; ++j) {
                m[j] = (r[j] + g[j] + bl[j]) * (1.0f/3.0f);
                s[j] = fmaf(r[j], r[j], fmaf(g[j], g[j], bl[j]*bl[j])) * (1.0f/3.0f);
            }
            *(float4*)&smM[iy][ix] = make_float4(m[0], m[1], m[2], m[3]);
            *(float4*)&smS[iy][ix] = make_float4(s[0], s[1], s[2], s[3]);
        }
    } else {
        for (int i = t; i < NPX; i += 512) {
            int iy = i / IWn;
            int ix = i - iy * IWn;
            int gy = reflectI(y0 - PADW + iy, HH);
            int gx = reflectI(x0 - PADW + ix, WW);
            size_t idx = (size_t)gy * WW + gx;
            float r  = pR[idx];
            float g  = pG[idx];
            float bl = pB[idx];
            smM[iy][ix] = (r + g + bl) * (1.0f/3.0f);
            smS[iy][ix] = fmaf(r, r, fmaf(g, g, bl*bl)) * (1.0f/3.0f);
        }
    }
    __syncthreads();

    // ---- early sat loads (T14): issue now, latency hides under stage 2 ----
    const int r  = t >> 4;          // 0..31 output row
    const int c4 = (t & 15) * 4;    // 0..60 output col group
    const size_t ro = (size_t)(y0 + r) * WW + x0 + c4;
    const float4 ra = *(const float4*)(pR + ro);
    const float4 ga = *(const float4*)(pG + ro);
    const float4 ba = *(const float4*)(pB + ro);

    // ---- stage 2: vertical 25-tap scalar forward scans (352 tasks) ----
    // seg0: outputs 0..15, reads rows 0..39, writes rows 0..15 (in place).
    // seg1: outputs 16..31, reads rows 16..55, writes rows 40..55 (dead halo).
    // Per column forward order => read-before-write; cross-task address sets
    // are disjoint => no barrier needed between segments.
    if (t < NT2) {
        int rem = t;
        float (*buf)[IWS] = smM;
        if (rem >= 2 * IWn) { buf = smS; rem -= 2 * IWn; }
        const bool seg1 = (rem >= IWn);
        const int  x    = seg1 ? rem - IWn : rem;

        if (!seg1) {
            float old = buf[0][x];
            float run = old;
#pragma unroll
            for (int k = 1; k < PS; ++k) run += buf[k][x];
            buf[0][x] = run;
#pragma unroll
            for (int y = 1; y < 16; ++y) {
                float cur = buf[y][x];              // original value
                run += buf[y + PS - 1][x] - old;
                buf[y][x] = run;
                old = cur;
            }
        } else {
            float run = 0.f;
#pragma unroll
            for (int k = 16; k < 16 + PS; ++k) run += buf[k][x];
            buf[40][x] = run;                       // output row 16 -> row 40
#pragma unroll
            for (int y = 17; y < 32; ++y) {
                float nw = buf[y + PS - 1][x];      // read row y+24 (original)
                run += nw - buf[y - 1][x];          // rows 16..30: original
                buf[y + PS - 1][x] = run;           // park at row y+24
            }
        }
    }
    __syncthreads();

    // ---- stage 3: horizontal 25-tap + sat + final (512 tasks exactly) ----
    const int vr = (r < 16) ? r : r + 24;   // vertical-sum row location

    float wm[28], ws[28];
#pragma unroll
    for (int i = 0; i < 7; ++i) {
        float4 a = *(const float4*)&smM[vr][c4 + 4*i];
        float4 c = *(const float4*)&smS[vr][c4 + 4*i];
        wm[4*i]=a.x; wm[4*i+1]=a.y; wm[4*i+2]=a.z; wm[4*i+3]=a.w;
        ws[4*i]=c.x; ws[4*i+1]=c.y; ws[4*i+2]=c.z; ws[4*i+3]=c.w;
    }
    float hm = 0.f, hs = 0.f;
#pragma unroll
    for (int i = 0; i < PS; ++i) { hm += wm[i]; hs += ws[i]; }

    float rr[4] = {ra.x, ra.y, ra.z, ra.w};
    float gg[4] = {ga.x, ga.y, ga.z, ga.w};
    float bb[4] = {ba.x, ba.y, ba.z, ba.w};

    float sc[4];
#pragma unroll
    for (int j = 0; j < 4; ++j) {
        if (j > 0) {
            hm += wm[PS - 1 + j] - wm[j - 1];
            hs += ws[PS - 1 + j] - ws[j - 1];
        }
        float mx = fmaxf(rr[j], fmaxf(gg[j], bb[j]));
        float mn = fminf(rr[j], fminf(gg[j], bb[j]));
        float sat = (mx - mn + EPSV) * fastrcp(mx + EPSV);

        float mean     = hm * INV625;
        float msq      = hs * INV625;
        float contrast = fmaf(-mean, mean, msq);
        float expo     = fabsf(mean - 0.5f) + EPSV;
        sc[j] = sat * contrast * fastrcp(expo);
    }
    float* orow = out + ((size_t)b * HH + (y0 + r)) * WW + x0 + c4;
    *(float4*)orow = make_float4(sc[0], sc[1], sc[2], sc[3]);
}

extern "C" void kernel_launch(void* const* d_in, const int* in_sizes, int n_in,
                              void* d_out, int out_size, void* d_ws, size_t ws_size,
                              hipStream_t stream)
{
    const float* img = (const float*)d_in[0];
    float* out = (float*)d_out;

    dim3 grid(WW / TW, HH / TH, NB);   // 8 x 16 x 16 = 2048 blocks
    fused_tile<<<grid, 512, 0, stream>>>(img, out);
}